// Round 17
// baseline (190.206 us; speedup 1.0000x reference)
//
#include <hip/hip_runtime.h>
#include <stdint.h>

typedef __attribute__((ext_vector_type(8))) short short8;
typedef __attribute__((ext_vector_type(4))) float f32x4;
typedef __attribute__((ext_vector_type(16))) float f32x16;
typedef __attribute__((ext_vector_type(4))) float float4v;
typedef __attribute__((ext_vector_type(4))) unsigned short ushort4v;
typedef __attribute__((ext_vector_type(2))) unsigned int uint2v;
typedef __attribute__((ext_vector_type(4))) unsigned int uint4v;

#define MFMA16(a,b,c) __builtin_amdgcn_mfma_f32_16x16x32_bf16((a),(b),(c),0,0,0)
#define MFMA32(a,b,c) __builtin_amdgcn_mfma_f32_32x32x16_bf16((a),(b),(c),0,0,0)

typedef const __attribute__((address_space(1))) void gld_src_t;
typedef __attribute__((address_space(3))) void gld_dst_t;
#define GLOAD_LDS16(g, l) __builtin_amdgcn_global_load_lds((gld_src_t*)(g), (gld_dst_t*)(l), 16, 0, 0)

__device__ __forceinline__ unsigned short f2bf(float f) {
  union { float f; unsigned int u; } v; v.f = f;
  unsigned int u = v.u;
  unsigned int r = (u + 0x7fffu + ((u >> 16) & 1u)) >> 16;  // RNE
  return (unsigned short)r;
}

// hardware packed f32x2 -> bf16x2 (RNE), low = a, high = b
__device__ __forceinline__ unsigned cvtpk(float a, float b) {
  unsigned r;
  asm("v_cvt_pk_bf16_f32 %0, %1, %2" : "=v"(r) : "v"(a), "v"(b));
  return r;
}

// single v_exp_f32 (2^x) via compiler intrinsic (v11 lesson: raw inline-asm
// trans op loses the compiler's result-delay handling -> stale consumers).
__device__ __forceinline__ float fexp2(float x) {
  return __builtin_amdgcn_exp2f(x);
}

// pack 8 f32 (two float4) -> short8 bf16 fragment via hw cvtpk
__device__ __forceinline__ short8 pack_bf8(float4v a0, float4v a1) {
  uint4v pk;
  pk[0] = cvtpk(a0[0], a0[1]);
  pk[1] = cvtpk(a0[2], a0[3]);
  pk[2] = cvtpk(a1[0], a1[1]);
  pk[3] = cvtpk(a1[2], a1[3]);
  return __builtin_bit_cast(short8, pk);
}

// ------------- transpose+convert W [K][N] f32 -> WT [N][K] bf16 -------------
__global__ __launch_bounds__(256) void cvt_transpose(const float* __restrict__ W,
                                                     unsigned short* __restrict__ WT,
                                                     int K, int N) {
  __shared__ unsigned short lds[64][72];
  int k0 = blockIdx.x * 64, n0 = blockIdx.y * 64;
  int t = threadIdx.x, tr = t >> 4, tc = t & 15;
#pragma unroll
  for (int p = 0; p < 4; ++p) {
    int k = tr + p * 16;
    float4v v = *(const float4v*)&W[(size_t)(k0 + k) * N + n0 + tc * 4];
    lds[tc * 4 + 0][k] = f2bf(v[0]);
    lds[tc * 4 + 1][k] = f2bf(v[1]);
    lds[tc * 4 + 2][k] = f2bf(v[2]);
    lds[tc * 4 + 3][k] = f2bf(v[3]);
  }
  __syncthreads();
#pragma unroll
  for (int p = 0; p < 4; ++p) {
    int n = tr + p * 16;
    ushort4v o;
    o[0] = lds[n][tc * 4 + 0]; o[1] = lds[n][tc * 4 + 1];
    o[2] = lds[n][tc * 4 + 2]; o[3] = lds[n][tc * 4 + 3];
    *(ushort4v*)&WT[(size_t)(n0 + n) * K + k0 + tc * 4] = o;
  }
}

// ===== v19: gemm_qkv reads x DIRECTLY as f32 (cvt_f32_bf16 kernel deleted) =====
// v18 audit: cvt_f32_bf16 moved 48MB (7.6us + a launch) solely to pre-convert
// x->bf16. Fuse: stage f32 A-tiles straight from x via global_load_lds (16KB/buf),
// convert LDS->fragment with cvtpk (VALUBusy ~20% in gemm -> headroom). Net HBM
// -32MB. A-swizzle mirrors verified v14 pattern: linear dest, source quad
// g=(l&7)^(l>>3), read slot (2hi)^(lo&7) -> 2-way banks (free, m136).
// B-side/barrier structure unchanged from v18 (2 K-steps per __syncthreads pair,
// 3 blocks/CU via launch_bounds). gemm_out keeps the bf16-A mainloop.
__device__ __forceinline__ void gemm_mainloop_f32A(const float* __restrict__ A,
                                                   const unsigned short* __restrict__ BT,
                                                   int K, int row0, int col0,
                                                   float (*Afl)[4096],
                                                   unsigned short (*Bls)[4096],
                                                   f32x4 acc[4][4]) {
  int t = threadIdx.x;
  int w = t >> 6, l = t & 63;
  int lo = l & 15, hi = l >> 4;
  int wr = w >> 1, wc = w & 1;
  // ---- A staging (f32): 16 instrs/K-step (4/wave). instr i of wave w covers
  // rows w*32+8i .. +7; lane l: row +=(l>>3), dest slot l&7 (16B quads).
  // stored slot = globalquad ^ (row&7) -> source quad = (l&7)^(l>>3).
  int aq = ((l & 7) ^ (l >> 3));
  const float* Agb = A + (size_t)(row0 + w * 32 + (l >> 3)) * 1024 + aq * 4;
  // ---- B staging (bf16): unchanged v18 geometry ----
  int srcC = (l & 3) ^ ((l >> 2) & 3) ^ ((l >> 4) & 3);
  const unsigned short* Bg1 = BT + (size_t)(col0 + (t >> 2)) * K + srcC * 8;
  const unsigned short* Bg2 = BT + (size_t)(col0 + 64 + (t >> 2)) * K + srcC * 8;
  int d1 = w * 512, d2 = 2048 + w * 512;   // ushort offsets within a B buffer
  // ---- fragment read offsets ----
  // A (f32): row R = wr*64+m*16+lo; want quads 2hi,2hi+1 at slots (2hi)^ (lo&7), ^1
  int fa = lo & 7;
  int aoff[4];
#pragma unroll
  for (int m = 0; m < 4; ++m)
    aoff[m] = (wr * 64 + m * 16 + lo) * 32 + (((2 * hi) ^ fa) << 2);
  int aflip = 4 * (((2 * hi) ^ fa) ^ ((2 * hi + 1) ^ fa));  // +/- slot delta... use direct
  (void)aflip;
  int aoff1[4];
#pragma unroll
  for (int m = 0; m < 4; ++m)
    aoff1[m] = (wr * 64 + m * 16 + lo) * 32 + (((2 * hi + 1) ^ fa) << 2);
  // B (bf16): unchanged
  int fs = (lo & 3) ^ ((lo >> 2) & 3);
  int boff[4];
#pragma unroll
  for (int n = 0; n < 4; ++n) boff[n] = (wc * 64 + n * 16 + lo) * 32 + ((hi ^ fs) << 3);

  for (int k0 = 0; k0 < K; k0 += 64) {
    // stage K-steps k0 (buf0) and k0+32 (buf1)
#pragma unroll
    for (int b = 0; b < 2; ++b) {
      int kk = k0 + b * 32;
#pragma unroll
      for (int i = 0; i < 4; ++i)
        GLOAD_LDS16(Agb + kk + (size_t)i * 8 * 1024, Afl[b] + w * 1024 + i * 256);
      GLOAD_LDS16(Bg1 + kk, Bls[b] + d1);
      GLOAD_LDS16(Bg2 + kk, Bls[b] + d2);
    }
    __syncthreads();
#pragma unroll
    for (int b = 0; b < 2; ++b) {
      short8 af[4], bf[4];
#pragma unroll
      for (int m = 0; m < 4; ++m) {
        float4v a0 = *(const float4v*)&Afl[b][aoff[m]];
        float4v a1 = *(const float4v*)&Afl[b][aoff1[m]];
        af[m] = pack_bf8(a0, a1);
      }
#pragma unroll
      for (int n = 0; n < 4; ++n) bf[n] = *(const short8*)&Bls[b][boff[n]];
#pragma unroll
      for (int m = 0; m < 4; ++m)
#pragma unroll
        for (int n = 0; n < 4; ++n)
          acc[m][n] = MFMA16(af[m], bf[n], acc[m][n]);
    }
    __syncthreads();
  }
}

// ===== 128x128 bf16 GEMM mainloop (v18, unchanged): for gemm_out =====
__device__ __forceinline__ void gemm_mainloop_128(const unsigned short* __restrict__ A,
                                                  const unsigned short* __restrict__ BT,
                                                  int K, int row0, int col0,
                                                  unsigned short (*Als)[4096],
                                                  unsigned short (*Bls)[4096],
                                                  f32x4 acc[4][4]) {
  int t = threadIdx.x;
  int w = t >> 6, l = t & 63;
  int lo = l & 15, hi = l >> 4;
  int wr = w >> 1, wc = w & 1;
  int srcC = (l & 3) ^ ((l >> 2) & 3) ^ ((l >> 4) & 3);
  const unsigned short* Ag1 = A + (size_t)(row0 + (t >> 2)) * K + srcC * 8;
  const unsigned short* Ag2 = A + (size_t)(row0 + 64 + (t >> 2)) * K + srcC * 8;
  const unsigned short* Bg1 = BT + (size_t)(col0 + (t >> 2)) * K + srcC * 8;
  const unsigned short* Bg2 = BT + (size_t)(col0 + 64 + (t >> 2)) * K + srcC * 8;
  int d1 = w * 512, d2 = 2048 + w * 512;
  int fs = (lo & 3) ^ ((lo >> 2) & 3);
  int aoff[4], boff[4];
#pragma unroll
  for (int m = 0; m < 4; ++m) aoff[m] = (wr * 64 + m * 16 + lo) * 32 + ((hi ^ fs) << 3);
#pragma unroll
  for (int n = 0; n < 4; ++n) boff[n] = (wc * 64 + n * 16 + lo) * 32 + ((hi ^ fs) << 3);

  for (int k0 = 0; k0 < K; k0 += 64) {
    GLOAD_LDS16(Ag1 + k0, Als[0] + d1);
    GLOAD_LDS16(Ag2 + k0, Als[0] + d2);
    GLOAD_LDS16(Bg1 + k0, Bls[0] + d1);
    GLOAD_LDS16(Bg2 + k0, Bls[0] + d2);
    GLOAD_LDS16(Ag1 + k0 + 32, Als[1] + d1);
    GLOAD_LDS16(Ag2 + k0 + 32, Als[1] + d2);
    GLOAD_LDS16(Bg1 + k0 + 32, Bls[1] + d1);
    GLOAD_LDS16(Bg2 + k0 + 32, Bls[1] + d2);
    __syncthreads();
    short8 af[4], bf[4];
#pragma unroll
    for (int m = 0; m < 4; ++m) af[m] = *(const short8*)&Als[0][aoff[m]];
#pragma unroll
    for (int n = 0; n < 4; ++n) bf[n] = *(const short8*)&Bls[0][boff[n]];
#pragma unroll
    for (int m = 0; m < 4; ++m)
#pragma unroll
      for (int n = 0; n < 4; ++n)
        acc[m][n] = MFMA16(af[m], bf[n], acc[m][n]);
    short8 af1[4], bf1[4];
#pragma unroll
    for (int m = 0; m < 4; ++m) af1[m] = *(const short8*)&Als[1][aoff[m]];
#pragma unroll
    for (int n = 0; n < 4; ++n) bf1[n] = *(const short8*)&Bls[1][boff[n]];
#pragma unroll
    for (int m = 0; m < 4; ++m)
#pragma unroll
      for (int n = 0; n < 4; ++n)
        acc[m][n] = MFMA16(af1[m], bf1[n], acc[m][n]);
    __syncthreads();
  }
}

// -- GEMM1: x(f32) @ W_qkvT + b -> Q(*0.125*log2e)/K [bh][s][64], V TRANSPOSED --
__global__ __launch_bounds__(256, 3) void gemm_qkv(const float* __restrict__ x,
                                                   const unsigned short* __restrict__ WT,
                                                   const float* __restrict__ bias,
                                                   unsigned short* __restrict__ Q,
                                                   unsigned short* __restrict__ Ko,
                                                   unsigned short* __restrict__ Vt) {
  __shared__ float Afl[2][4096];               // 2 x 16KB f32 A tiles
  __shared__ unsigned short Bls[2][4096];      // 2 x 8KB bf16 B tiles
  f32x4 zero = {0.f, 0.f, 0.f, 0.f};
  f32x4 acc[4][4];
#pragma unroll
  for (int m = 0; m < 4; ++m)
#pragma unroll
    for (int n = 0; n < 4; ++n) acc[m][n] = zero;
  int row0 = blockIdx.x * 128, col0 = blockIdx.y * 128;
  gemm_mainloop_f32A(x, WT, 1024, row0, col0, Afl, Bls, acc);

  int t = threadIdx.x, w = t >> 6, l = t & 63, lo = l & 15, hi = l >> 4;
  int wr = w >> 1, wc = w & 1;
#pragma unroll
  for (int m = 0; m < 4; ++m) {
#pragma unroll
    for (int n = 0; n < 4; ++n) {
      int col = col0 + wc * 64 + n * 16 + lo;
      float b = bias[col];
      int which = col >> 10, hd = col & 1023, h = hd >> 6, d = hd & 63;
      int row = row0 + wr * 64 + m * 16 + hi * 4;
      int bb = row >> 11, s = row & 2047;
      if (which == 2) {
        ushort4v o;
#pragma unroll
        for (int r = 0; r < 4; ++r) o[r] = f2bf(acc[m][n][r] + b);
        *(ushort4v*)&Vt[((size_t)(bb * 16 + h) * 64 + d) * 2048 + s] = o;
      } else if (which == 0) {
        size_t base = ((size_t)(bb * 16 + h) * 2048 + s) * 64 + d;
#pragma unroll
        for (int r = 0; r < 4; ++r)
          Q[base + (size_t)r * 64] = f2bf((acc[m][n][r] + b) * 0.18033688011112042f);
      } else {
        size_t base = ((size_t)(bb * 16 + h) * 2048 + s) * 64 + d;
#pragma unroll
        for (int r = 0; r < 4; ++r)
          Ko[base + (size_t)r * 64] = f2bf(acc[m][n][r] + b);
      }
    }
  }
}

// ---------------- GEMM2: attn @ W_outT + b_out -> fp32 out ----------------
__global__ __launch_bounds__(256, 3) void gemm_out(const unsigned short* __restrict__ attn,
                                                   const unsigned short* __restrict__ WT,
                                                   const float* __restrict__ bias,
                                                   float* __restrict__ out) {
  __shared__ unsigned short Als[2][4096], Bls[2][4096];
  f32x4 zero = {0.f, 0.f, 0.f, 0.f};
  f32x4 acc[4][4];
#pragma unroll
  for (int m = 0; m < 4; ++m)
#pragma unroll
    for (int n = 0; n < 4; ++n) acc[m][n] = zero;
  int row0 = blockIdx.x * 128, col0 = blockIdx.y * 128;
  gemm_mainloop_128(attn, WT, 1024, row0, col0, Als, Bls, acc);

  int t = threadIdx.x, w = t >> 6, l = t & 63, lo = l & 15, hi = l >> 4;
  int wr = w >> 1, wc = w & 1;
#pragma unroll
  for (int m = 0; m < 4; ++m) {
#pragma unroll
    for (int n = 0; n < 4; ++n) {
      int col = col0 + wc * 64 + n * 16 + lo;
      float b = bias[col];
#pragma unroll
      for (int r = 0; r < 4; ++r) {
        int row = row0 + wr * 64 + m * 16 + hi * 4 + r;
        out[(size_t)row * 1024 + col] = acc[m][n][r] + b;
      }
    }
  }
}

// ===== flash attention v12 (unchanged): fixed-shift softmax + exp2 intrinsic =====
__global__ __launch_bounds__(256, 3) void attn_fwd2(const unsigned short* __restrict__ Q,
                                                    const unsigned short* __restrict__ Kg,
                                                    const unsigned short* __restrict__ Vt,
                                                    unsigned short* __restrict__ attn_out) {
  const int S = 2048;
  __shared__ unsigned short Kls[3][4096];   // [buf][64 rows][8 slots x 16B] swizzled
  __shared__ unsigned short Vls[3][4096];   // [buf][64 d   ][8 slots x 16B] swizzled

  int bid = blockIdx.x;
  int swz = (bid & 7) * 128 + (bid >> 3);   // XCD c covers bh = c*8..c*8+7
  int bh = swz >> 4, qt = swz & 15;
  int t = threadIdx.x, w = t >> 6, l = t & 63;
  int lo = l & 31, hi = l >> 5;
  int qi = qt * 128 + w * 32 + lo;
  const unsigned short* Qr = Q + ((size_t)bh * S + qi) * 64 + hi * 8;
  const char* KbB = (const char*)(Kg + (size_t)bh * S * 64);
  const char* VbB = (const char*)(Vt + (size_t)bh * 64 * S);

  short8 qf[4];
#pragma unroll
  for (int ks = 0; ks < 4; ++ks) qf[ks] = *(const short8*)(Qr + ks * 16);

  // ones A-fragment (bf16 1.0) for the lsum MFMA
  short8 onesf;
#pragma unroll
  for (int e = 0; e < 8; ++e) onesf[e] = (short)0x3F80;

  // ---- staging geometry: 16 gload_lds per tile (4/wave), 1KB contiguous each ----
  int lrow = l >> 3;                                     // 0..7 (row&7 within instr)
  int j0 = w * 2;                                        // this wave's 2 K + 2 V instrs
  int g0B = (((l & 7) ^ lrow ^ j0) << 4);                // source chunk bytes, instr j0
  int g1B = (((l & 7) ^ lrow ^ (j0 + 1)) << 4);          // source chunk bytes, instr j0+1
  size_t kg0 = (size_t)(8 * j0 + lrow) * 128 + g0B;      // + kv0*128
  size_t kg1 = (size_t)(8 * j0 + 8 + lrow) * 128 + g1B;
  size_t vg0 = (size_t)(8 * j0 + lrow) * 4096 + g0B;     // + kv0*2
  size_t vg1 = (size_t)(8 * j0 + 8 + lrow) * 4096 + g1B;

  // ---- fragment read offsets (ushort idx), loop-invariant ----
  int koff0[4], koff1[4];
#pragma unroll
  for (int ks = 0; ks < 4; ++ks) {
    int srow = (lo & 7) ^ (lo >> 3);
    koff0[ks] = lo * 64 + (((2 * ks + hi) ^ srow) << 3);
    koff1[ks] = (lo + 32) * 64 + (((2 * ks + hi) ^ srow ^ 4) << 3);
  }

#define STAGE_KV(Kd, Vd, kvoff) do {                                  \
    GLOAD_LDS16(KbB + (size_t)(kvoff) * 128 + kg0, (Kd) + j0 * 512);  \
    GLOAD_LDS16(KbB + (size_t)(kvoff) * 128 + kg1, (Kd) + (j0 + 1) * 512); \
    GLOAD_LDS16(VbB + (size_t)(kvoff) * 2 + vg0, (Vd) + j0 * 512);    \
    GLOAD_LDS16(VbB + (size_t)(kvoff) * 2 + vg1, (Vd) + (j0 + 1) * 512); \
  } while (0)

  // rotating buffer pointers: read Kc/Vc; stage 2-ahead into K2/V2
  unsigned short *Kc = &Kls[0][0], *K1 = &Kls[1][0], *K2 = &Kls[2][0];
  unsigned short *Vc = &Vls[0][0], *V1 = &Vls[1][0], *V2 = &Vls[2][0];

  // ---- prologue: stage tiles 0,1 (8 loads/wave in flight) ----
  STAGE_KV(Kc, Vc, 0);
  STAGE_KV(K1, V1, 64);

  const f32x16 zf = {0.f,0.f,0.f,0.f,0.f,0.f,0.f,0.f,0.f,0.f,0.f,0.f,0.f,0.f,0.f,0.f};
  f32x16 ot0 = zf, ot1 = zf;
  f32x16 lacc = zf;               // denominator accumulator: only lacc[0] is ever read

  for (int it = 0; it < 32; ++it) {
    // wait ONLY for the tile staged 2 iters ago (4 newer loads stay in flight)
    asm volatile("s_waitcnt vmcnt(4)" ::: "memory");
    __builtin_amdgcn_s_barrier();
    // stage tile it+2 into the buffer read at iter it-1 (wrap: harmless re-stage)
    STAGE_KV(K2, V2, ((it + 2) & 31) * 64);

    // ---- K fragments from LDS (conflict-free swizzled b128 reads) ----
    short8 kf0[4], kf1[4];
#pragma unroll
    for (int ks = 0; ks < 4; ++ks) {
      kf0[ks] = *(const short8*)&Kc[koff0[ks]];
      kf1[ks] = *(const short8*)&Kc[koff1[ks]];
    }
    f32x16 st0 = zf, st1 = zf;
    __builtin_amdgcn_s_setprio(1);
#pragma unroll
    for (int ks = 0; ks < 4; ++ks) {
      st0 = MFMA32(kf0[ks], qf[ks], st0);
      st1 = MFMA32(kf1[ks], qf[ks], st1);
    }
    __builtin_amdgcn_s_setprio(0);
    // ---- V fragments (time-share regs with kf; overlap reads with exp/pack) ----
    short8 vf0[4], vf1[4];
#pragma unroll
    for (int ks = 0; ks < 4; ++ks) {
      vf0[ks] = *(const short8*)&Vc[koff0[ks]];
      vf1[ks] = *(const short8*)&Vc[koff1[ks]];
    }

    // ---- fixed-shift softmax numerator: P = exp2(st), pack to PV B-operand ----
    short8 pb[4];
    float p[16];
    // phase A: st0 -> pb[0], pb[1]
#pragma unroll
    for (int r = 0; r < 16; ++r) p[r] = fexp2(st0[r]);
    {
      unsigned x0 = cvtpk(p[0], p[1]),  x1 = cvtpk(p[2], p[3]);
      unsigned y0 = cvtpk(p[4], p[5]),  y1 = cvtpk(p[6], p[7]);
      uint2v sw0 = __builtin_amdgcn_permlane32_swap(x0, y0, false, false);
      uint2v sw1 = __builtin_amdgcn_permlane32_swap(x1, y1, false, false);
      uint4v pk; pk[0] = sw0[0]; pk[1] = sw1[0]; pk[2] = sw0[1]; pk[3] = sw1[1];
      pb[0] = __builtin_bit_cast(short8, pk);
      unsigned x2 = cvtpk(p[8], p[9]),  x3 = cvtpk(p[10], p[11]);
      unsigned y2 = cvtpk(p[12], p[13]), y3 = cvtpk(p[14], p[15]);
      uint2v sw2 = __builtin_amdgcn_permlane32_swap(x2, y2, false, false);
      uint2v sw3 = __builtin_amdgcn_permlane32_swap(x3, y3, false, false);
      uint4v pk1; pk1[0] = sw2[0]; pk1[1] = sw3[0]; pk1[2] = sw2[1]; pk1[3] = sw3[1];
      pb[1] = __builtin_bit_cast(short8, pk1);
    }
    // phase B: st1 -> pb[2], pb[3] (reuses p[] registers)
#pragma unroll
    for (int r = 0; r < 16; ++r) p[r] = fexp2(st1[r]);
    {
      unsigned x0 = cvtpk(p[0], p[1]),  x1 = cvtpk(p[2], p[3]);
      unsigned y0 = cvtpk(p[4], p[5]),  y1 = cvtpk(p[6], p[7]);
      uint2v sw0 = __builtin_amdgcn_permlane32_swap(x0, y0, false, false);
      uint2v sw1 = __builtin_amdgcn_permlane32_swap(x1, y1, false, false);
      uint4v pk; pk[0] = sw0[0]; pk[1] = sw1[0]; pk[2] = sw0[1]; pk[3] = sw1[1];
      pb[2] = __builtin_bit_cast(short8, pk);
      unsigned x2 = cvtpk(p[8], p[9]),  x3 = cvtpk(p[10], p[11]);
      unsigned y2 = cvtpk(p[12], p[13]), y3 = cvtpk(p[14], p[15]);
      uint2v sw2 = __builtin_amdgcn_permlane32_swap(x2, y2, false, false);
      uint2v sw3 = __builtin_amdgcn_permlane32_swap(x3, y3, false, false);
      uint4v pk1; pk1[0] = sw2[0]; pk1[1] = sw3[0]; pk1[2] = sw2[1]; pk1[3] = sw3[1];
      pb[3] = __builtin_bit_cast(short8, pk1);
    }

    // ---- PV + denominator (ones-row) on the matrix pipe ----
    __builtin_amdgcn_s_setprio(1);
#pragma unroll
    for (int ks = 0; ks < 4; ++ks) {
      ot0 = MFMA32(vf0[ks], pb[ks], ot0);
      ot1 = MFMA32(vf1[ks], pb[ks], ot1);
      lacc = MFMA32(onesf, pb[ks], lacc);   // D[i][q] = sum_k P[k][q] (all rows equal)
    }
    __builtin_amdgcn_s_setprio(0);

    // rotate buffers: (cur,1,2) -> (1,2,cur)
    unsigned short* tk = Kc; Kc = K1; K1 = K2; K2 = tk;
    unsigned short* tv = Vc; Vc = V1; V1 = V2; V2 = tv;
  }

  // ---- finalize: inv = 1/lacc[0] (full-k sum, per-lane q), store bf16 ----
  float inv = 1.0f / lacc[0];
  int b = bh >> 4, h = bh & 15;
  unsigned short* orow = attn_out + ((size_t)(b * 2048 + qi)) * 1024 + h * 64 + 4 * hi;
#pragma unroll
  for (int g = 0; g < 4; ++g) {
    uint2v u0, u1;
    u0[0] = cvtpk(ot0[4*g + 0] * inv, ot0[4*g + 1] * inv);
    u0[1] = cvtpk(ot0[4*g + 2] * inv, ot0[4*g + 3] * inv);
    u1[0] = cvtpk(ot1[4*g + 0] * inv, ot1[4*g + 1] * inv);
    u1[1] = cvtpk(ot1[4*g + 2] * inv, ot1[4*g + 3] * inv);
    *(uint2v*)(orow + 8 * g) = u0;         // d = 8g+4hi+0..3
    *(uint2v*)(orow + 32 + 8 * g) = u1;    // d = 32+8g+4hi+0..3
  }
}

extern "C" void kernel_launch(void* const* d_in, const int* in_sizes, int n_in,
                              void* d_out, int out_size, void* d_ws, size_t ws_size,
                              hipStream_t stream) {
  (void)in_sizes; (void)n_in; (void)out_size; (void)ws_size;
  const float* x     = (const float*)d_in[0];
  const float* W_qkv = (const float*)d_in[1];
  const float* b_qkv = (const float*)d_in[2];
  const float* W_out = (const float*)d_in[3];
  const float* b_out = (const float*)d_in[4];
  float* out = (float*)d_out;
  char* ws = (char*)d_ws;
  unsigned short* WqkvT = (unsigned short*)(ws + 16777216);  // 3072x1024 bf16
  unsigned short* WoutT = (unsigned short*)(ws + 23068672);  // 1024x1024 bf16
  unsigned short* Qb    = (unsigned short*)(ws + 25165824);  // 64x2048x64 bf16
  unsigned short* Kb    = (unsigned short*)(ws + 41943040);  // 64x2048x64 bf16
  unsigned short* Vtb   = (unsigned short*)(ws + 75497472);  // 64x64x2048 bf16 (direct)
  unsigned short* attnb = (unsigned short*)(ws + 92274688);  // 8192x1024 bf16

  cvt_transpose<<<dim3(16, 48), 256, 0, stream>>>(W_qkv, WqkvT, 1024, 3072);
  cvt_transpose<<<dim3(16, 16), 256, 0, stream>>>(W_out, WoutT, 1024, 1024);
  gemm_qkv<<<dim3(64, 24), 256, 0, stream>>>(x, WqkvT, b_qkv, Qb, Kb, Vtb);
  attn_fwd2<<<1024, 256, 0, stream>>>(Qb, Kb, Vtb, attnb);
  gemm_out<<<dim3(64, 8), 256, 0, stream>>>(attnb, WoutT, b_out, out);
}

// Round 18
// 182.808 us; speedup vs baseline: 1.0405x; 1.0405x over previous
//
#include <hip/hip_runtime.h>
#include <stdint.h>

typedef __attribute__((ext_vector_type(8))) short short8;
typedef __attribute__((ext_vector_type(4))) float f32x4;
typedef __attribute__((ext_vector_type(16))) float f32x16;
typedef __attribute__((ext_vector_type(4))) float float4v;
typedef __attribute__((ext_vector_type(4))) unsigned short ushort4v;
typedef __attribute__((ext_vector_type(2))) unsigned int uint2v;
typedef __attribute__((ext_vector_type(4))) unsigned int uint4v;

#define MFMA16(a,b,c) __builtin_amdgcn_mfma_f32_16x16x32_bf16((a),(b),(c),0,0,0)
#define MFMA32(a,b,c) __builtin_amdgcn_mfma_f32_32x32x16_bf16((a),(b),(c),0,0,0)

typedef const __attribute__((address_space(1))) void gld_src_t;
typedef __attribute__((address_space(3))) void gld_dst_t;
#define GLOAD_LDS16(g, l) __builtin_amdgcn_global_load_lds((gld_src_t*)(g), (gld_dst_t*)(l), 16, 0, 0)

__device__ __forceinline__ unsigned short f2bf(float f) {
  union { float f; unsigned int u; } v; v.f = f;
  unsigned int u = v.u;
  unsigned int r = (u + 0x7fffu + ((u >> 16) & 1u)) >> 16;  // RNE
  return (unsigned short)r;
}

// hardware packed f32x2 -> bf16x2 (RNE), low = a, high = b
__device__ __forceinline__ unsigned cvtpk(float a, float b) {
  unsigned r;
  asm("v_cvt_pk_bf16_f32 %0, %1, %2" : "=v"(r) : "v"(a), "v"(b));
  return r;
}

// single v_exp_f32 (2^x) via compiler intrinsic (v11 lesson: raw inline-asm
// trans op loses the compiler's result-delay handling -> stale consumers).
__device__ __forceinline__ float fexp2(float x) {
  return __builtin_amdgcn_exp2f(x);
}

// ---------------- convert fp32 -> bf16, vectorized ----------------
__global__ __launch_bounds__(256) void cvt_f32_bf16(const float* __restrict__ in,
                                                    unsigned short* __restrict__ out) {
  int i = blockIdx.x * 256 + threadIdx.x;
  float4v v = ((const float4v*)in)[i];
  ushort4v o;
  o[0] = f2bf(v[0]); o[1] = f2bf(v[1]); o[2] = f2bf(v[2]); o[3] = f2bf(v[3]);
  ((ushort4v*)out)[i] = o;
}

// ------------- transpose+convert W [K][N] f32 -> WT [N][K] bf16 -------------
__global__ __launch_bounds__(256) void cvt_transpose(const float* __restrict__ W,
                                                     unsigned short* __restrict__ WT,
                                                     int K, int N) {
  __shared__ unsigned short lds[64][72];
  int k0 = blockIdx.x * 64, n0 = blockIdx.y * 64;
  int t = threadIdx.x, tr = t >> 4, tc = t & 15;
#pragma unroll
  for (int p = 0; p < 4; ++p) {
    int k = tr + p * 16;
    float4v v = *(const float4v*)&W[(size_t)(k0 + k) * N + n0 + tc * 4];
    lds[tc * 4 + 0][k] = f2bf(v[0]);
    lds[tc * 4 + 1][k] = f2bf(v[1]);
    lds[tc * 4 + 2][k] = f2bf(v[2]);
    lds[tc * 4 + 3][k] = f2bf(v[3]);
  }
  __syncthreads();
#pragma unroll
  for (int p = 0; p < 4; ++p) {
    int n = tr + p * 16;
    ushort4v o;
    o[0] = lds[n][tc * 4 + 0]; o[1] = lds[n][tc * 4 + 1];
    o[2] = lds[n][tc * 4 + 2]; o[3] = lds[n][tc * 4 + 3];
    *(ushort4v*)&WT[(size_t)(n0 + n) * K + k0 + tc * 4] = o;
  }
}

// ===== 128x128 bf16 GEMM mainloop (v18 FINAL): 2 K-steps per barrier, 32KB LDS =====
// v19 post-mortem: fusing the x->bf16 conversion into gemm_qkv (f32-A staging)
// REGRESSED (FETCH 49->64MB: f32 A doubles traffic that the pre-conversion pass
// amortized across 24 column-blocks; conflicts +50%; extra cvtpk on the critical
// path). Reverted. This v18 structure is the session best: 2-buffer plain
// __syncthreads (v16 barrier amortization), verified-harmless chunk swizzle,
// __launch_bounds__(256,3) occupancy cap -> 3 blocks/CU (v18 win).
__device__ __forceinline__ void gemm_mainloop_128(const unsigned short* __restrict__ A,
                                                  const unsigned short* __restrict__ BT,
                                                  int K, int row0, int col0,
                                                  unsigned short (*Als)[4096],
                                                  unsigned short (*Bls)[4096],
                                                  f32x4 acc[4][4]) {
  int t = threadIdx.x;
  int w = t >> 6, l = t & 63;
  int lo = l & 15, hi = l >> 4;
  int wr = w >> 1, wc = w & 1;
  // staging: lane l -> LDS row w*16+(l>>2) (half1) / +64 (half2), slot l&3.
  // source chunk = slot ^ f(row), f(row)=(row&3)^((row>>2)&3)
  int srcC = (l & 3) ^ ((l >> 2) & 3) ^ ((l >> 4) & 3);
  const unsigned short* Ag1 = A + (size_t)(row0 + (t >> 2)) * K + srcC * 8;
  const unsigned short* Ag2 = A + (size_t)(row0 + 64 + (t >> 2)) * K + srcC * 8;
  const unsigned short* Bg1 = BT + (size_t)(col0 + (t >> 2)) * K + srcC * 8;
  const unsigned short* Bg2 = BT + (size_t)(col0 + 64 + (t >> 2)) * K + srcC * 8;
  int d1 = w * 512, d2 = 2048 + w * 512;   // ushort offsets within a buffer
  // fragment reads: row R = {wr|wc}*64+m*16+lo; chunk hi lives at slot hi^f(R),
  // f(R) = (lo&3)^((lo>>2)&3)
  int fs = (lo & 3) ^ ((lo >> 2) & 3);
  int aoff[4], boff[4];
#pragma unroll
  for (int m = 0; m < 4; ++m) aoff[m] = (wr * 64 + m * 16 + lo) * 32 + ((hi ^ fs) << 3);
#pragma unroll
  for (int n = 0; n < 4; ++n) boff[n] = (wc * 64 + n * 16 + lo) * 32 + ((hi ^ fs) << 3);

  for (int k0 = 0; k0 < K; k0 += 64) {
    // stage K-steps k0 (buf0) and k0+32 (buf1): 8 gload_lds per wave
    GLOAD_LDS16(Ag1 + k0, Als[0] + d1);
    GLOAD_LDS16(Ag2 + k0, Als[0] + d2);
    GLOAD_LDS16(Bg1 + k0, Bls[0] + d1);
    GLOAD_LDS16(Bg2 + k0, Bls[0] + d2);
    GLOAD_LDS16(Ag1 + k0 + 32, Als[1] + d1);
    GLOAD_LDS16(Ag2 + k0 + 32, Als[1] + d2);
    GLOAD_LDS16(Bg1 + k0 + 32, Bls[1] + d1);
    GLOAD_LDS16(Bg2 + k0 + 32, Bls[1] + d2);
    __syncthreads();
    short8 af[4], bf[4];
#pragma unroll
    for (int m = 0; m < 4; ++m) af[m] = *(const short8*)&Als[0][aoff[m]];
#pragma unroll
    for (int n = 0; n < 4; ++n) bf[n] = *(const short8*)&Bls[0][boff[n]];
#pragma unroll
    for (int m = 0; m < 4; ++m)
#pragma unroll
      for (int n = 0; n < 4; ++n)
        acc[m][n] = MFMA16(af[m], bf[n], acc[m][n]);
    short8 af1[4], bf1[4];
#pragma unroll
    for (int m = 0; m < 4; ++m) af1[m] = *(const short8*)&Als[1][aoff[m]];
#pragma unroll
    for (int n = 0; n < 4; ++n) bf1[n] = *(const short8*)&Bls[1][boff[n]];
#pragma unroll
    for (int m = 0; m < 4; ++m)
#pragma unroll
      for (int n = 0; n < 4; ++n)
        acc[m][n] = MFMA16(af1[m], bf1[n], acc[m][n]);
    __syncthreads();
  }
}

// -- GEMM1: xb @ W_qkvT + b -> Q(*0.125*log2e)/K [bh][s][64], V directly TRANSPOSED --
__global__ __launch_bounds__(256, 3) void gemm_qkv(const unsigned short* __restrict__ xb,
                                                   const unsigned short* __restrict__ WT,
                                                   const float* __restrict__ bias,
                                                   unsigned short* __restrict__ Q,
                                                   unsigned short* __restrict__ Ko,
                                                   unsigned short* __restrict__ Vt) {
  __shared__ unsigned short Als[2][4096], Bls[2][4096];
  f32x4 zero = {0.f, 0.f, 0.f, 0.f};
  f32x4 acc[4][4];
#pragma unroll
  for (int m = 0; m < 4; ++m)
#pragma unroll
    for (int n = 0; n < 4; ++n) acc[m][n] = zero;
  int row0 = blockIdx.x * 128, col0 = blockIdx.y * 128;
  gemm_mainloop_128(xb, WT, 1024, row0, col0, Als, Bls, acc);

  int t = threadIdx.x, w = t >> 6, l = t & 63, lo = l & 15, hi = l >> 4;
  int wr = w >> 1, wc = w & 1;
#pragma unroll
  for (int m = 0; m < 4; ++m) {
#pragma unroll
    for (int n = 0; n < 4; ++n) {
      int col = col0 + wc * 64 + n * 16 + lo;
      float b = bias[col];
      int which = col >> 10, hd = col & 1023, h = hd >> 6, d = hd & 63;
      int row = row0 + wr * 64 + m * 16 + hi * 4;
      int bb = row >> 11, s = row & 2047;
      if (which == 2) {
        ushort4v o;
#pragma unroll
        for (int r = 0; r < 4; ++r) o[r] = f2bf(acc[m][n][r] + b);
        *(ushort4v*)&Vt[((size_t)(bb * 16 + h) * 64 + d) * 2048 + s] = o;
      } else if (which == 0) {
        size_t base = ((size_t)(bb * 16 + h) * 2048 + s) * 64 + d;
#pragma unroll
        for (int r = 0; r < 4; ++r)
          Q[base + (size_t)r * 64] = f2bf((acc[m][n][r] + b) * 0.18033688011112042f);
      } else {
        size_t base = ((size_t)(bb * 16 + h) * 2048 + s) * 64 + d;
#pragma unroll
        for (int r = 0; r < 4; ++r)
          Ko[base + (size_t)r * 64] = f2bf(acc[m][n][r] + b);
      }
    }
  }
}

// ---------------- GEMM2: attn @ W_outT + b_out -> fp32 out ----------------
__global__ __launch_bounds__(256, 3) void gemm_out(const unsigned short* __restrict__ attn,
                                                   const unsigned short* __restrict__ WT,
                                                   const float* __restrict__ bias,
                                                   float* __restrict__ out) {
  __shared__ unsigned short Als[2][4096], Bls[2][4096];
  f32x4 zero = {0.f, 0.f, 0.f, 0.f};
  f32x4 acc[4][4];
#pragma unroll
  for (int m = 0; m < 4; ++m)
#pragma unroll
    for (int n = 0; n < 4; ++n) acc[m][n] = zero;
  int row0 = blockIdx.x * 128, col0 = blockIdx.y * 128;
  gemm_mainloop_128(attn, WT, 1024, row0, col0, Als, Bls, acc);

  int t = threadIdx.x, w = t >> 6, l = t & 63, lo = l & 15, hi = l >> 4;
  int wr = w >> 1, wc = w & 1;
#pragma unroll
  for (int m = 0; m < 4; ++m) {
#pragma unroll
    for (int n = 0; n < 4; ++n) {
      int col = col0 + wc * 64 + n * 16 + lo;
      float b = bias[col];
#pragma unroll
      for (int r = 0; r < 4; ++r) {
        int row = row0 + wr * 64 + m * 16 + hi * 4 + r;
        out[(size_t)row * 1024 + col] = acc[m][n][r] + b;
      }
    }
  }
}

// ===== flash attention v12 (unchanged): fixed-shift softmax + exp2 intrinsic =====
__global__ __launch_bounds__(256, 3) void attn_fwd2(const unsigned short* __restrict__ Q,
                                                    const unsigned short* __restrict__ Kg,
                                                    const unsigned short* __restrict__ Vt,
                                                    unsigned short* __restrict__ attn_out) {
  const int S = 2048;
  __shared__ unsigned short Kls[3][4096];   // [buf][64 rows][8 slots x 16B] swizzled
  __shared__ unsigned short Vls[3][4096];   // [buf][64 d   ][8 slots x 16B] swizzled

  int bid = blockIdx.x;
  int swz = (bid & 7) * 128 + (bid >> 3);   // XCD c covers bh = c*8..c*8+7
  int bh = swz >> 4, qt = swz & 15;
  int t = threadIdx.x, w = t >> 6, l = t & 63;
  int lo = l & 31, hi = l >> 5;
  int qi = qt * 128 + w * 32 + lo;
  const unsigned short* Qr = Q + ((size_t)bh * S + qi) * 64 + hi * 8;
  const char* KbB = (const char*)(Kg + (size_t)bh * S * 64);
  const char* VbB = (const char*)(Vt + (size_t)bh * 64 * S);

  short8 qf[4];
#pragma unroll
  for (int ks = 0; ks < 4; ++ks) qf[ks] = *(const short8*)(Qr + ks * 16);

  // ones A-fragment (bf16 1.0) for the lsum MFMA
  short8 onesf;
#pragma unroll
  for (int e = 0; e < 8; ++e) onesf[e] = (short)0x3F80;

  // ---- staging geometry: 16 gload_lds per tile (4/wave), 1KB contiguous each ----
  int lrow = l >> 3;                                     // 0..7 (row&7 within instr)
  int j0 = w * 2;                                        // this wave's 2 K + 2 V instrs
  int g0B = (((l & 7) ^ lrow ^ j0) << 4);                // source chunk bytes, instr j0
  int g1B = (((l & 7) ^ lrow ^ (j0 + 1)) << 4);          // source chunk bytes, instr j0+1
  size_t kg0 = (size_t)(8 * j0 + lrow) * 128 + g0B;      // + kv0*128
  size_t kg1 = (size_t)(8 * j0 + 8 + lrow) * 128 + g1B;
  size_t vg0 = (size_t)(8 * j0 + lrow) * 4096 + g0B;     // + kv0*2
  size_t vg1 = (size_t)(8 * j0 + 8 + lrow) * 4096 + g1B;

  // ---- fragment read offsets (ushort idx), loop-invariant ----
  int koff0[4], koff1[4];
#pragma unroll
  for (int ks = 0; ks < 4; ++ks) {
    int srow = (lo & 7) ^ (lo >> 3);
    koff0[ks] = lo * 64 + (((2 * ks + hi) ^ srow) << 3);
    koff1[ks] = (lo + 32) * 64 + (((2 * ks + hi) ^ srow ^ 4) << 3);
  }

#define STAGE_KV(Kd, Vd, kvoff) do {                                  \
    GLOAD_LDS16(KbB + (size_t)(kvoff) * 128 + kg0, (Kd) + j0 * 512);  \
    GLOAD_LDS16(KbB + (size_t)(kvoff) * 128 + kg1, (Kd) + (j0 + 1) * 512); \
    GLOAD_LDS16(VbB + (size_t)(kvoff) * 2 + vg0, (Vd) + j0 * 512);    \
    GLOAD_LDS16(VbB + (size_t)(kvoff) * 2 + vg1, (Vd) + (j0 + 1) * 512); \
  } while (0)

  // rotating buffer pointers: read Kc/Vc; stage 2-ahead into K2/V2
  unsigned short *Kc = &Kls[0][0], *K1 = &Kls[1][0], *K2 = &Kls[2][0];
  unsigned short *Vc = &Vls[0][0], *V1 = &Vls[1][0], *V2 = &Vls[2][0];

  // ---- prologue: stage tiles 0,1 (8 loads/wave in flight) ----
  STAGE_KV(Kc, Vc, 0);
  STAGE_KV(K1, V1, 64);

  const f32x16 zf = {0.f,0.f,0.f,0.f,0.f,0.f,0.f,0.f,0.f,0.f,0.f,0.f,0.f,0.f,0.f,0.f};
  f32x16 ot0 = zf, ot1 = zf;
  f32x16 lacc = zf;               // denominator accumulator: only lacc[0] is ever read

  for (int it = 0; it < 32; ++it) {
    // wait ONLY for the tile staged 2 iters ago (4 newer loads stay in flight)
    asm volatile("s_waitcnt vmcnt(4)" ::: "memory");
    __builtin_amdgcn_s_barrier();
    // stage tile it+2 into the buffer read at iter it-1 (wrap: harmless re-stage)
    STAGE_KV(K2, V2, ((it + 2) & 31) * 64);

    // ---- K fragments from LDS (conflict-free swizzled b128 reads) ----
    short8 kf0[4], kf1[4];
#pragma unroll
    for (int ks = 0; ks < 4; ++ks) {
      kf0[ks] = *(const short8*)&Kc[koff0[ks]];
      kf1[ks] = *(const short8*)&Kc[koff1[ks]];
    }
    f32x16 st0 = zf, st1 = zf;
    __builtin_amdgcn_s_setprio(1);
#pragma unroll
    for (int ks = 0; ks < 4; ++ks) {
      st0 = MFMA32(kf0[ks], qf[ks], st0);
      st1 = MFMA32(kf1[ks], qf[ks], st1);
    }
    __builtin_amdgcn_s_setprio(0);
    // ---- V fragments (time-share regs with kf; overlap reads with exp/pack) ----
    short8 vf0[4], vf1[4];
#pragma unroll
    for (int ks = 0; ks < 4; ++ks) {
      vf0[ks] = *(const short8*)&Vc[koff0[ks]];
      vf1[ks] = *(const short8*)&Vc[koff1[ks]];
    }

    // ---- fixed-shift softmax numerator: P = exp2(st), pack to PV B-operand ----
    short8 pb[4];
    float p[16];
    // phase A: st0 -> pb[0], pb[1]
#pragma unroll
    for (int r = 0; r < 16; ++r) p[r] = fexp2(st0[r]);
    {
      unsigned x0 = cvtpk(p[0], p[1]),  x1 = cvtpk(p[2], p[3]);
      unsigned y0 = cvtpk(p[4], p[5]),  y1 = cvtpk(p[6], p[7]);
      uint2v sw0 = __builtin_amdgcn_permlane32_swap(x0, y0, false, false);
      uint2v sw1 = __builtin_amdgcn_permlane32_swap(x1, y1, false, false);
      uint4v pk; pk[0] = sw0[0]; pk[1] = sw1[0]; pk[2] = sw0[1]; pk[3] = sw1[1];
      pb[0] = __builtin_bit_cast(short8, pk);
      unsigned x2 = cvtpk(p[8], p[9]),  x3 = cvtpk(p[10], p[11]);
      unsigned y2 = cvtpk(p[12], p[13]), y3 = cvtpk(p[14], p[15]);
      uint2v sw2 = __builtin_amdgcn_permlane32_swap(x2, y2, false, false);
      uint2v sw3 = __builtin_amdgcn_permlane32_swap(x3, y3, false, false);
      uint4v pk1; pk1[0] = sw2[0]; pk1[1] = sw3[0]; pk1[2] = sw2[1]; pk1[3] = sw3[1];
      pb[1] = __builtin_bit_cast(short8, pk1);
    }
    // phase B: st1 -> pb[2], pb[3] (reuses p[] registers)
#pragma unroll
    for (int r = 0; r < 16; ++r) p[r] = fexp2(st1[r]);
    {
      unsigned x0 = cvtpk(p[0], p[1]),  x1 = cvtpk(p[2], p[3]);
      unsigned y0 = cvtpk(p[4], p[5]),  y1 = cvtpk(p[6], p[7]);
      uint2v sw0 = __builtin_amdgcn_permlane32_swap(x0, y0, false, false);
      uint2v sw1 = __builtin_amdgcn_permlane32_swap(x1, y1, false, false);
      uint4v pk; pk[0] = sw0[0]; pk[1] = sw1[0]; pk[2] = sw0[1]; pk[3] = sw1[1];
      pb[2] = __builtin_bit_cast(short8, pk);
      unsigned x2 = cvtpk(p[8], p[9]),  x3 = cvtpk(p[10], p[11]);
      unsigned y2 = cvtpk(p[12], p[13]), y3 = cvtpk(p[14], p[15]);
      uint2v sw2 = __builtin_amdgcn_permlane32_swap(x2, y2, false, false);
      uint2v sw3 = __builtin_amdgcn_permlane32_swap(x3, y3, false, false);
      uint4v pk1; pk1[0] = sw2[0]; pk1[1] = sw3[0]; pk1[2] = sw2[1]; pk1[3] = sw3[1];
      pb[3] = __builtin_bit_cast(short8, pk1);
    }

    // ---- PV + denominator (ones-row) on the matrix pipe ----
    __builtin_amdgcn_s_setprio(1);
#pragma unroll
    for (int ks = 0; ks < 4; ++ks) {
      ot0 = MFMA32(vf0[ks], pb[ks], ot0);
      ot1 = MFMA32(vf1[ks], pb[ks], ot1);
      lacc = MFMA32(onesf, pb[ks], lacc);   // D[i][q] = sum_k P[k][q] (all rows equal)
    }
    __builtin_amdgcn_s_setprio(0);

    // rotate buffers: (cur,1,2) -> (1,2,cur)
    unsigned short* tk = Kc; Kc = K1; K1 = K2; K2 = tk;
    unsigned short* tv = Vc; Vc = V1; V1 = V2; V2 = tv;
  }

  // ---- finalize: inv = 1/lacc[0] (full-k sum, per-lane q), store bf16 ----
  float inv = 1.0f / lacc[0];
  int b = bh >> 4, h = bh & 15;
  unsigned short* orow = attn_out + ((size_t)(b * 2048 + qi)) * 1024 + h * 64 + 4 * hi;
#pragma unroll
  for (int g = 0; g < 4; ++g) {
    uint2v u0, u1;
    u0[0] = cvtpk(ot0[4*g + 0] * inv, ot0[4*g + 1] * inv);
    u0[1] = cvtpk(ot0[4*g + 2] * inv, ot0[4*g + 3] * inv);
    u1[0] = cvtpk(ot1[4*g + 0] * inv, ot1[4*g + 1] * inv);
    u1[1] = cvtpk(ot1[4*g + 2] * inv, ot1[4*g + 3] * inv);
    *(uint2v*)(orow + 8 * g) = u0;         // d = 8g+4hi+0..3
    *(uint2v*)(orow + 32 + 8 * g) = u1;    // d = 32+8g+4hi+0..3
  }
}

extern "C" void kernel_launch(void* const* d_in, const int* in_sizes, int n_in,
                              void* d_out, int out_size, void* d_ws, size_t ws_size,
                              hipStream_t stream) {
  (void)in_sizes; (void)n_in; (void)out_size; (void)ws_size;
  const float* x     = (const float*)d_in[0];
  const float* W_qkv = (const float*)d_in[1];
  const float* b_qkv = (const float*)d_in[2];
  const float* W_out = (const float*)d_in[3];
  const float* b_out = (const float*)d_in[4];
  float* out = (float*)d_out;
  char* ws = (char*)d_ws;
  unsigned short* xb    = (unsigned short*)(ws);             // 8192x1024 bf16
  unsigned short* WqkvT = (unsigned short*)(ws + 16777216);  // 3072x1024 bf16
  unsigned short* WoutT = (unsigned short*)(ws + 23068672);  // 1024x1024 bf16
  unsigned short* Qb    = (unsigned short*)(ws + 25165824);  // 64x2048x64 bf16
  unsigned short* Kb    = (unsigned short*)(ws + 41943040);  // 64x2048x64 bf16
  unsigned short* Vtb   = (unsigned short*)(ws + 75497472);  // 64x64x2048 bf16 (direct)
  unsigned short* attnb = (unsigned short*)(ws + 92274688);  // 8192x1024 bf16

  cvt_f32_bf16<<<8192, 256, 0, stream>>>(x, xb);
  cvt_transpose<<<dim3(16, 48), 256, 0, stream>>>(W_qkv, WqkvT, 1024, 3072);
  cvt_transpose<<<dim3(16, 16), 256, 0, stream>>>(W_out, WoutT, 1024, 1024);
  gemm_qkv<<<dim3(64, 24), 256, 0, stream>>>(xb, WqkvT, b_qkv, Qb, Kb, Vtb);
  attn_fwd2<<<1024, 256, 0, stream>>>(Qb, Kb, Vtb, attnb);
  gemm_out<<<dim3(64, 8), 256, 0, stream>>>(attnb, WoutT, b_out, out);
}